// Round 6
// baseline (386.376 us; speedup 1.0000x reference)
//
#include <hip/hip_runtime.h>
#include <cstdint>
#include <cmath>

typedef _Float16 f16;
typedef _Float16 f16x8 __attribute__((ext_vector_type(8)));
typedef float f32x4 __attribute__((ext_vector_type(4)));

// ---------------------------------------------------------------------------
// Build X1 = [enc_flat(10240) | word(512) | persona[speaker](512) | h0(512)] fp16
__global__ __launch_bounds__(256) void build_x1_kernel(
    const float* __restrict__ enc, const float* __restrict__ word,
    const float* __restrict__ pers, const int* __restrict__ speaker,
    const float* __restrict__ h0, f16* __restrict__ X)
{
  const int b  = blockIdx.y;
  const int k2 = blockIdx.x * 256 + threadIdx.x;   // 0..5887
  const int k  = k2 * 2;
  float v0, v1;
  if (k < 10240) {
    const float* p = enc + (long long)b * 10240 + k; v0 = p[0]; v1 = p[1];
  } else if (k < 10752) {
    const float* p = word + b * 512 + (k - 10240);   v0 = p[0]; v1 = p[1];
  } else if (k < 11264) {
    const float* p = pers + (long long)speaker[b] * 512 + (k - 10752); v0 = p[0]; v1 = p[1];
  } else {
    const float* p = h0 + b * 512 + (k - 11264);     v0 = p[0]; v1 = p[1];
  }
  union { f16 h[2]; unsigned int u; } pk;
  pk.h[0] = (f16)v0; pk.h[1] = (f16)v1;
  ((unsigned int*)X)[(long long)b * 5888 + k2] = pk.u;
}

// ---------------------------------------------------------------------------
// WsT[L][n][k] = fp16( W_L[k][n] + U_L[k][n] ) — layers 2-4 have x == h.
__global__ __launch_bounds__(256) void wsum_t_kernel(
    const float* __restrict__ W2, const float* __restrict__ U2,
    const float* __restrict__ W3, const float* __restrict__ U3,
    const float* __restrict__ W4, const float* __restrict__ U4,
    f16* __restrict__ out)
{
  const int t = blockIdx.x * 256 + threadIdx.x;
  const int L = blockIdx.y;
  const float* W = (L == 0) ? W2 : (L == 1) ? W3 : W4;
  const float* U = (L == 0) ? U2 : (L == 1) ? U3 : U4;
  const int n  = t & 2047;
  const int k0 = (t >> 11) << 6;
  f16* op = out + (long long)L * (2048 * 512) + (long long)n * 512 + k0;
  for (int kk = 0; kk < 64; kk += 8) {
    f16x8 v;
    #pragma unroll
    for (int j = 0; j < 8; j++) {
      const int k = k0 + kk + j;
      v[j] = (f16)(W[(long long)k * 2048 + n] + U[(long long)k * 2048 + n]);
    }
    *(f16x8*)(op + kk) = v;
  }
}

// ---------------------------------------------------------------------------
// Barrier-free direct-register MFMA GEMM. Wave tile 128m x 32n, per-wave
// independent (no LDS / no __syncthreads -> no vmcnt(0) drains).
// A fp16 loaded f16x8 in operand layout; B fp32 strided dwords -> cvt.
// K-loop manually unrolled by 2: buffers a0/b0 (even) and a1/b1 (odd) have
// STATIC roles -> full SROA, no scratch (R4's runtime-index spill bug).
// niter must be EVEN. wid = mt + 2*(nt + ntiles*ks).
#define LOAD_A(dst, kofs)                                                   \
  _Pragma("unroll")                                                         \
  for (int mf = 0; mf < 8; mf++)                                            \
    dst[mf] = *(const f16x8*)(Ab + (long long)mf * 16 * lda + (kofs));
#define LOAD_B(dst, kofs)                                                   \
  {                                                                         \
    const float* bp_ = Bp + (long long)(kofs) * ldb;                        \
    _Pragma("unroll")                                                       \
    for (int j = 0; j < 8; j++) {                                           \
      dst[j]     = bp_[(long long)j * ldb];                                 \
      dst[8 + j] = bp_[(long long)j * ldb + 16];                            \
    }                                                                       \
  }
#define STEP(aR, bR)                                                        \
  {                                                                         \
    f16x8 bf0_, bf1_;                                                       \
    _Pragma("unroll")                                                       \
    for (int j = 0; j < 8; j++) {                                           \
      bf0_[j] = (f16)bR[j];  bf1_[j] = (f16)bR[8 + j];                      \
    }                                                                       \
    _Pragma("unroll")                                                       \
    for (int mf = 0; mf < 8; mf++) {                                        \
      acc[mf][0] = __builtin_amdgcn_mfma_f32_16x16x32_f16(aR[mf], bf0_, acc[mf][0], 0, 0, 0); \
      acc[mf][1] = __builtin_amdgcn_mfma_f32_16x16x32_f16(aR[mf], bf1_, acc[mf][1], 0, 0, 0); \
    }                                                                       \
  }

__global__ __launch_bounds__(256, 2) void gemm_direct(
    const f16* __restrict__ A, int lda,
    const float* __restrict__ B0, const float* __restrict__ B1, int ksw, int ldb,
    int ntiles, int kchunk,
    void* __restrict__ Cv, int ldc, long long c_split_stride, int store_f16)
{
  const int lane = threadIdx.x & 63;
  const int wid  = blockIdx.x * 4 + (threadIdx.x >> 6);
  const int mt = wid & 1;
  const int nt = (wid >> 1) % ntiles;
  const int ks = wid / (2 * ntiles);
  const int m0 = mt * 128;
  const int n0 = nt * 32;
  const int kbeg = ks * kchunk;
  const int lj = lane & 15, quad = lane >> 4;

  // whole k-chunk lies in one of B0/B1 (kchunk | ksw alignment guaranteed by host)
  const float* Bbase;
  int koff;
  if (kbeg >= ksw) { Bbase = B1; koff = kbeg - ksw; }
  else             { Bbase = B0; koff = kbeg; }
  const float* Bp = Bbase + (long long)(koff + quad * 8) * ldb + n0 + lj;
  const f16*   Ab = A + (long long)(m0 + lj) * lda + kbeg + quad * 8;

  f32x4 acc[8][2] = {};
  f16x8 a0[8], a1[8];
  float b0[16], b1[16];

  const int niter = kchunk >> 5;    // even
  LOAD_A(a0, 0);
  LOAD_B(b0, 0);
  for (int kt = 0; kt < niter; kt += 2) {
    if (kt + 1 < niter) { LOAD_A(a1, (kt + 1) * 32); LOAD_B(b1, (kt + 1) * 32); }
    STEP(a0, b0);
    if (kt + 2 < niter) { LOAD_A(a0, (kt + 2) * 32); LOAD_B(b0, (kt + 2) * 32); }
    if (kt + 1 < niter) STEP(a1, b1);
  }

  // C/D: col = lane&15, row = quad*4 + r
  if (store_f16) {
    f16* Cs = (f16*)Cv + (long long)ks * c_split_stride;
    #pragma unroll
    for (int mf = 0; mf < 8; mf++) {
      const int r0 = m0 + mf * 16 + quad * 4;
      #pragma unroll
      for (int nf = 0; nf < 2; nf++) {
        const int cc = n0 + nf * 16 + lj;
        #pragma unroll
        for (int r = 0; r < 4; r++)
          Cs[(long long)(r0 + r) * ldc + cc] = (f16)acc[mf][nf][r];
      }
    }
  } else {
    float* Cs = (float*)Cv + (long long)ks * c_split_stride;
    #pragma unroll
    for (int mf = 0; mf < 8; mf++) {
      const int r0 = m0 + mf * 16 + quad * 4;
      #pragma unroll
      for (int nf = 0; nf < 2; nf++) {
        const int cc = n0 + nf * 16 + lj;
        #pragma unroll
        for (int r = 0; r < 4; r++)
          Cs[(long long)(r0 + r) * ldc + cc] = acc[mf][nf][r];
      }
    }
  }
}

// ---------------------------------------------------------------------------
// Small LSTM layer, barrier-free, in-register, SSA double buffer.
// 512 single-wave blocks; wave tile 16m x 16j x 4 gates, K = 512.
__global__ __launch_bounds__(64) void lstm_small_layer(
    const f16* __restrict__ h_in,          // [256][512] fp16
    const f16* __restrict__ WsT,           // [2048][512] fp16 (W+U)^T
    const float* __restrict__ bias,
    const float* __restrict__ c_prev, float* __restrict__ c_out,
    f16* __restrict__ h16_out, float* __restrict__ h32_out)
{
  const int lane = threadIdx.x;
  const int wid  = blockIdx.x;           // 512 waves
  const int jt = wid & 31, mt = wid >> 5;   // mt 0..15
  const int m0 = mt * 16, j0 = jt * 16;
  const int lj = lane & 15, quad = lane >> 4;

  const f16* Ab = h_in + (long long)(m0 + lj) * 512 + quad * 8;
  const f16* Bb = WsT + (long long)(j0 + lj) * 512 + quad * 8;
  const long long GS = 512LL * 512;      // gate stride in WsT

  f32x4 g0 = {}, g1 = {}, g2 = {}, g3 = {};

  f16x8 ca = *(const f16x8*)(Ab);
  f16x8 cb0 = *(const f16x8*)(Bb);
  f16x8 cb1 = *(const f16x8*)(Bb + GS);
  f16x8 cb2 = *(const f16x8*)(Bb + 2 * GS);
  f16x8 cb3 = *(const f16x8*)(Bb + 3 * GS);

  #pragma unroll
  for (int kt = 0; kt < 16; kt++) {
    f16x8 na = ca, nb0 = cb0, nb1 = cb1, nb2 = cb2, nb3 = cb3;
    if (kt < 15) {
      const int k = (kt + 1) * 32;
      na  = *(const f16x8*)(Ab + k);
      nb0 = *(const f16x8*)(Bb + k);
      nb1 = *(const f16x8*)(Bb + GS + k);
      nb2 = *(const f16x8*)(Bb + 2 * GS + k);
      nb3 = *(const f16x8*)(Bb + 3 * GS + k);
    }
    g0 = __builtin_amdgcn_mfma_f32_16x16x32_f16(ca, cb0, g0, 0, 0, 0);
    g1 = __builtin_amdgcn_mfma_f32_16x16x32_f16(ca, cb1, g1, 0, 0, 0);
    g2 = __builtin_amdgcn_mfma_f32_16x16x32_f16(ca, cb2, g2, 0, 0, 0);
    g3 = __builtin_amdgcn_mfma_f32_16x16x32_f16(ca, cb3, g3, 0, 0, 0);
    ca = na; cb0 = nb0; cb1 = nb1; cb2 = nb2; cb3 = nb3;
  }

  const float bi = bias[j0 + lj],        bfv = bias[512 + j0 + lj];
  const float bg = bias[1024 + j0 + lj], bo  = bias[1536 + j0 + lj];
  #pragma unroll
  for (int r = 0; r < 4; r++) {
    const int m = m0 + quad * 4 + r;
    const int idx = m * 512 + j0 + lj;
    const float gi = 1.f / (1.f + expf(-(g0[r] + bi)));
    const float gf = 1.f / (1.f + expf(-(g1[r] + bfv)));
    const float gg = fmaxf(g2[r] + bg, 0.f);
    const float go = 1.f / (1.f + expf(-(g3[r] + bo)));
    const float cn = gf * c_prev[idx] + gi * gg;
    const float hn = go * fmaxf(cn, 0.f);
    c_out[idx] = cn;
    h16_out[idx] = (f16)hn;
    if (h32_out) h32_out[idx] = hn;
  }
}

// ---------------------------------------------------------------------------
// L1 gate: reduce nsplit fp16 split-K partials + bias, apply gates.
__global__ __launch_bounds__(256) void gate_kernel(
    const unsigned int* __restrict__ zbase, int nsplit,
    const float* __restrict__ bias,
    const float* __restrict__ c_prev, float* __restrict__ c_out,
    f16* __restrict__ h16_out)
{
  const int idx2 = blockIdx.x * 256 + threadIdx.x;  // 0..65535
  const int b  = idx2 >> 8;
  const int j2 = idx2 & 255;
  const int j  = j2 * 2;
  float z[4][2];
  #pragma unroll
  for (int g = 0; g < 4; g++) { z[g][0] = bias[g * 512 + j]; z[g][1] = bias[g * 512 + j + 1]; }
  for (int s = 0; s < nsplit; s++) {
    const unsigned int* zp = zbase + (long long)s * 262144 + b * 1024;
    #pragma unroll
    for (int g = 0; g < 4; g++) {
      union { unsigned int u; f16 h[2]; } v;
      v.u = zp[g * 256 + j2];
      z[g][0] += (float)v.h[0];
      z[g][1] += (float)v.h[1];
    }
  }
  #pragma unroll
  for (int e = 0; e < 2; e++) {
    const float gi = 1.f / (1.f + expf(-z[0][e]));
    const float gf = 1.f / (1.f + expf(-z[1][e]));
    const float gg = fmaxf(z[2][e], 0.f);
    const float go = 1.f / (1.f + expf(-z[3][e]));
    const int idx = b * 512 + j + e;
    const float cn = gf * c_prev[idx] + gi * gg;
    const float hn = go * fmaxf(cn, 0.f);
    c_out[idx] = cn;
    h16_out[idx] = (f16)hn;
  }
}

// ---------------------------------------------------------------------------
// In-place softmax over V=32000 per row, float4 path. 1024 thr/row.
__global__ __launch_bounds__(1024) void softmax_kernel(
    float* __restrict__ logits, const float* __restrict__ bd)
{
  const int row = blockIdx.x;
  const int t = threadIdx.x;
  float4* rp = (float4*)(logits + (long long)row * 32000);   // 8000 float4
  const float4* bp = (const float4*)bd;
  float4 l[8];
  float m = -1e30f;
  #pragma unroll
  for (int i = 0; i < 8; i++) {
    const int v = t + i * 1024;
    if (v < 8000) {
      float4 x = rp[v]; const float4 bb = bp[v];
      x.x += bb.x; x.y += bb.y; x.z += bb.z; x.w += bb.w;
      l[i] = x;
      m = fmaxf(m, fmaxf(fmaxf(x.x, x.y), fmaxf(x.z, x.w)));
    } else {
      l[i] = make_float4(-1e30f, -1e30f, -1e30f, -1e30f);
    }
  }
  #pragma unroll
  for (int off = 32; off > 0; off >>= 1) m = fmaxf(m, __shfl_xor(m, off, 64));
  __shared__ float redm[16];
  __shared__ float reds[16];
  const int w = t >> 6;
  if ((t & 63) == 0) redm[w] = m;
  __syncthreads();
  float bm = redm[0];
  #pragma unroll
  for (int i = 1; i < 16; i++) bm = fmaxf(bm, redm[i]);
  float s = 0.f;
  #pragma unroll
  for (int i = 0; i < 8; i++) {
    const float ex = expf(l[i].x - bm), ey = expf(l[i].y - bm);
    const float ez = expf(l[i].z - bm), ew = expf(l[i].w - bm);
    l[i] = make_float4(ex, ey, ez, ew);
    s += (ex + ey) + (ez + ew);
  }
  #pragma unroll
  for (int off = 32; off > 0; off >>= 1) s += __shfl_xor(s, off, 64);
  if ((t & 63) == 0) reds[w] = s;
  __syncthreads();
  float ts = 0.f;
  #pragma unroll
  for (int i = 0; i < 16; i++) ts += reds[i];
  const float inv = 1.0f / ts;
  #pragma unroll
  for (int i = 0; i < 8; i++) {
    const int v = t + i * 1024;
    if (v < 8000) {
      float4 x = l[i];
      x.x *= inv; x.y *= inv; x.z *= inv; x.w *= inv;
      rp[v] = x;
    }
  }
}

// ---------------------------------------------------------------------------
extern "C" void kernel_launch(void* const* d_in, const int* in_sizes, int n_in,
                              void* d_out, int out_size, void* d_ws, size_t ws_size,
                              hipStream_t stream) {
  const float* enc     = (const float*)d_in[0];
  const float* word    = (const float*)d_in[1];
  const float* h0      = (const float*)d_in[2];
  const float* c0      = (const float*)d_in[3];
  const int*   speaker = (const int*)d_in[4];
  const float* pers = (const float*)d_in[6];
  const float* W1 = (const float*)d_in[7];
  const float* U1 = (const float*)d_in[8];
  const float* b1 = (const float*)d_in[9];
  const float* W2 = (const float*)d_in[10];
  const float* U2 = (const float*)d_in[11];
  const float* b2 = (const float*)d_in[12];
  const float* W3 = (const float*)d_in[13];
  const float* U3 = (const float*)d_in[14];
  const float* b3 = (const float*)d_in[15];
  const float* W4 = (const float*)d_in[16];
  const float* U4 = (const float*)d_in[17];
  const float* b4 = (const float*)d_in[18];
  const float* Wd = (const float*)d_in[19];
  const float* bd = (const float*)d_in[20];

  float* out = (float*)d_out;
  float* h4_out = out + 8192000;
  float* c4_out = out + 8192000 + 131072;

  // d_ws layout (>= 40 MB used; harness provides ~352 MB):
  f16*   hA   = (f16*)d_ws;                            // 256 KB
  f16*   hB   = (f16*)((char*)d_ws + 262144);          // 256 KB
  f16*   hC   = (f16*)((char*)d_ws + 524288);          // 256 KB
  float* cbuf = (float*)((char*)d_ws + 786432);        // 512 KB
  f16*   WsT  = (f16*)((char*)d_ws + 2097152);         // 6 MB  [2..8 MB)
  f16*   X1h  = (f16*)((char*)d_ws + 8388608);         // 6 MB  [8..14.1 MB)
  f16*   zp16 = (f16*)((char*)d_ws + 16777216);        // 23 MB [16..39 MB)

  const int BIG = 1 << 29;
  const long long LW = 2048LL * 512;

  build_x1_kernel<<<dim3(23, 256), 256, 0, stream>>>(enc, word, pers, speaker, h0, X1h);
  wsum_t_kernel<<<dim3(64, 3), 256, 0, stream>>>(W2, U2, W3, U3, W4, U4, WsT);

  // layer 1: K = 11776 = 23 splits x 512 (16 even iters);
  // waves = 2 x 64 x 23 = 2944 -> 736 blocks
  gemm_direct<<<dim3(736), 256, 0, stream>>>(
      X1h, 11776, W1, U1, 11264, 2048, 64, 512, zp16, 2048, 524288LL, 1);
  gate_kernel<<<dim3(256), 256, 0, stream>>>((const unsigned int*)zp16, 23, b1, c0, cbuf, hA);

  // layers 2-4: z = h @ (W+U), K=512, 512 single-wave blocks each
  lstm_small_layer<<<dim3(512), 64, 0, stream>>>(hA, WsT,          b2, cbuf, cbuf, hB, nullptr);
  lstm_small_layer<<<dim3(512), 64, 0, stream>>>(hB, WsT + LW,     b3, cbuf, cbuf, hA, nullptr);
  lstm_small_layer<<<dim3(512), 64, 0, stream>>>(hA, WsT + 2 * LW, b4, cbuf, c4_out, hC, h4_out);

  // decoder: logits = h4 @ Wd, fp32; waves = 2 x 1000 -> 500 blocks
  gemm_direct<<<dim3(500), 256, 0, stream>>>(
      hC, 512, Wd, Wd, BIG, 32000, 1000, 512, out, 32000, 0LL, 0);

  softmax_kernel<<<dim3(256), 1024, 0, stream>>>(out, bd);
}

// Round 7
// 335.681 us; speedup vs baseline: 1.1510x; 1.1510x over previous
//
#include <hip/hip_runtime.h>
#include <cstdint>
#include <cmath>

typedef _Float16 f16;
typedef _Float16 f16x8 __attribute__((ext_vector_type(8)));
typedef float f32x4 __attribute__((ext_vector_type(4)));

// async 16B/lane global->LDS (lds dst = wave-uniform base + lane*16)
__device__ inline void gld_lds16(const void* g, void* l) {
  __builtin_amdgcn_global_load_lds(
      (__attribute__((address_space(1))) void*)(uintptr_t)g,
      (__attribute__((address_space(3))) void*)l, 16, 0, 0);
}

// ---------------------------------------------------------------------------
// Build X1 = [enc_flat(10240) | word(512) | persona[speaker](512) | h0(512)] fp16
__global__ __launch_bounds__(256) void build_x1_kernel(
    const float* __restrict__ enc, const float* __restrict__ word,
    const float* __restrict__ pers, const int* __restrict__ speaker,
    const float* __restrict__ h0, f16* __restrict__ X)
{
  const int b  = blockIdx.y;
  const int k2 = blockIdx.x * 256 + threadIdx.x;   // 0..5887
  const int k  = k2 * 2;
  float v0, v1;
  if (k < 10240) {
    const float* p = enc + (long long)b * 10240 + k; v0 = p[0]; v1 = p[1];
  } else if (k < 10752) {
    const float* p = word + b * 512 + (k - 10240);   v0 = p[0]; v1 = p[1];
  } else if (k < 11264) {
    const float* p = pers + (long long)speaker[b] * 512 + (k - 10752); v0 = p[0]; v1 = p[1];
  } else {
    const float* p = h0 + b * 512 + (k - 11264);     v0 = p[0]; v1 = p[1];
  }
  union { f16 h[2]; unsigned int u; } pk;
  pk.h[0] = (f16)v0; pk.h[1] = (f16)v1;
  ((unsigned int*)X)[(long long)b * 5888 + k2] = pk.u;
}

// ---------------------------------------------------------------------------
// WsT[L][n][k] = fp16( W_L[k][n] + U_L[k][n] ) — layers 2-4 have x == h.
__global__ __launch_bounds__(256) void wsum_t_kernel(
    const float* __restrict__ W2, const float* __restrict__ U2,
    const float* __restrict__ W3, const float* __restrict__ U3,
    const float* __restrict__ W4, const float* __restrict__ U4,
    f16* __restrict__ out)
{
  const int t = blockIdx.x * 256 + threadIdx.x;
  const int L = blockIdx.y;
  const float* W = (L == 0) ? W2 : (L == 1) ? W3 : W4;
  const float* U = (L == 0) ? U2 : (L == 1) ? U3 : U4;
  const int n  = t & 2047;
  const int k0 = (t >> 11) << 6;
  f16* op = out + (long long)L * (2048 * 512) + (long long)n * 512 + k0;
  for (int kk = 0; kk < 64; kk += 8) {
    f16x8 v;
    #pragma unroll
    for (int j = 0; j < 8; j++) {
      const int k = k0 + kk + j;
      v[j] = (f16)(W[(long long)k * 2048 + n] + U[(long long)k * 2048 + n]);
    }
    *(f16x8*)(op + kk) = v;
  }
}

// ---------------------------------------------------------------------------
// Pipelined fp16 MFMA GEMM, BM=256 (all rows -> B read exactly once per
// split), BN=128, BK=32. 256 thr = 4 waves (2m x 2n), wave tile 128x64.
// Double-buffered LDS, prefetch of iter k+1 issued before compute of iter k.
// A fp16 via global_load_lds (chunk-swizzled rows of 32h); B fp32->fp16,
// float2/thread, [n][40] padded. grid = (n_tiles, splits).
__global__ __launch_bounds__(256, 2) void gemm_pipe2(
    const f16* __restrict__ A, int lda,
    const float* __restrict__ B0, const float* __restrict__ B1, int ksw, int ldb,
    void* __restrict__ Cv, int ldc, long long c_split_stride, int niter,
    int store_f16)
{
  __shared__ __align__(16) f16 Ah[2][256 * 32];   // 2 x 16 KB
  __shared__ __align__(16) f16 Bh[2][128 * 40];   // 2 x 10 KB

  const int tid  = threadIdx.x;
  const int lane = tid & 63;
  const int wave = tid >> 6;
  const int n0 = blockIdx.x * 128;
  const int kbeg = blockIdx.y * (niter * 32);

  // A staging lane map (verified R2-R5): within each 1KB/16-row segment,
  // lane -> row lane>>2, stored chunk lane&3, actual k-chunk (lane&3)^((lane>>3)&3)
  const int a_row16 = lane >> 2;
  const int a_ksub  = ((lane & 3) ^ ((lane >> 3) & 3)) * 8;

  // B staging: thread -> 2 adjacent cols, one 8-k octet (256 thr = 128x4)
  const int nl0  = (tid & 63) * 2;
  const int koct = tid >> 6;          // 0..3

  float2 bv[8];

  auto issueB = [&](int kt) {
    const int kb = kbeg + kt * 32 + koct * 8;
    #pragma unroll
    for (int i = 0; i < 8; i++) {
      const int krow = kb + i;
      const float* bp = (krow >= ksw) ? (B1 + (long long)(krow - ksw) * ldb)
                                      : (B0 + (long long)krow * ldb);
      bv[i] = *(const float2*)(bp + n0 + nl0);
    }
  };
  auto issueA = [&](int kt) {
    const int akb = kbeg + kt * 32;
    #pragma unroll
    for (int half = 0; half < 4; half++) {
      const int rb = wave * 64 + half * 16;      // 4 waves x 64 rows = 256
      const f16* gp = A + (long long)(rb + a_row16) * lda + akb + a_ksub;
      gld_lds16((const void*)gp, (void*)&Ah[kt & 1][rb * 32]);
    }
  };
  auto writeB = [&](int kt) {
    f16x8 p0, p1;
    #pragma unroll
    for (int i = 0; i < 8; i++) { p0[i] = (f16)bv[i].x; p1[i] = (f16)bv[i].y; }
    *(f16x8*)&Bh[kt & 1][(nl0    ) * 40 + koct * 8] = p0;
    *(f16x8*)&Bh[kt & 1][(nl0 + 1) * 40 + koct * 8] = p1;
  };

  const int wm = (wave & 1) * 128;
  const int wn = (wave >> 1) * 64;
  f32x4 acc[8][4] = {};

  issueB(0); issueA(0); writeB(0);
  __syncthreads();

  for (int kt = 0; kt < niter; kt++) {
    const int buf = kt & 1;
    const bool more = (kt + 1 < niter);
    if (more) { issueB(kt + 1); issueA(kt + 1); }

    f16x8 bf[4];
    #pragma unroll
    for (int ni = 0; ni < 4; ni++) {
      const int n = wn + ni * 16 + (lane & 15);
      bf[ni] = *(const f16x8*)&Bh[buf][n * 40 + (lane >> 4) * 8];
    }
    #pragma unroll
    for (int mi = 0; mi < 8; mi++) {
      const int m = wm + mi * 16 + (lane & 15);
      const f16x8 af = *(const f16x8*)&Ah[buf][m * 32 + (((lane >> 4) ^ ((m >> 1) & 3)) * 8)];
      #pragma unroll
      for (int ni = 0; ni < 4; ni++)
        acc[mi][ni] = __builtin_amdgcn_mfma_f32_16x16x32_f16(af, bf[ni], acc[mi][ni], 0, 0, 0);
    }

    if (more) writeB(kt + 1);
    __syncthreads();
  }

  // C/D: col = lane&15, row = (lane>>4)*4 + r
  if (store_f16) {
    f16* Cs = (f16*)Cv + (long long)blockIdx.y * c_split_stride;
    #pragma unroll
    for (int mi = 0; mi < 8; mi++) {
      const int r0 = wm + mi * 16 + (lane >> 4) * 4;
      #pragma unroll
      for (int ni = 0; ni < 4; ni++) {
        const int cc = n0 + wn + ni * 16 + (lane & 15);
        #pragma unroll
        for (int r = 0; r < 4; r++)
          Cs[(long long)(r0 + r) * ldc + cc] = (f16)acc[mi][ni][r];
      }
    }
  } else {
    float* Cs = (float*)Cv + (long long)blockIdx.y * c_split_stride;
    #pragma unroll
    for (int mi = 0; mi < 8; mi++) {
      const int r0 = wm + mi * 16 + (lane >> 4) * 4;
      #pragma unroll
      for (int ni = 0; ni < 4; ni++) {
        const int cc = n0 + wn + ni * 16 + (lane & 15);
        #pragma unroll
        for (int r = 0; r < 4; r++)
          Cs[(long long)(r0 + r) * ldc + cc] = acc[mi][ni][r];
      }
    }
  }
}

// ---------------------------------------------------------------------------
// Small LSTM layer, barrier-free, in-register, SSA double buffer.
// 512 single-wave blocks; wave tile 16m x 16j x 4 gates, K = 512.
__global__ __launch_bounds__(64) void lstm_small_layer(
    const f16* __restrict__ h_in,          // [256][512] fp16
    const f16* __restrict__ WsT,           // [2048][512] fp16 (W+U)^T
    const float* __restrict__ bias,
    const float* __restrict__ c_prev, float* __restrict__ c_out,
    f16* __restrict__ h16_out, float* __restrict__ h32_out)
{
  const int lane = threadIdx.x;
  const int wid  = blockIdx.x;           // 512 waves
  const int jt = wid & 31, mt = wid >> 5;   // mt 0..15
  const int m0 = mt * 16, j0 = jt * 16;
  const int lj = lane & 15, quad = lane >> 4;

  const f16* Ab = h_in + (long long)(m0 + lj) * 512 + quad * 8;
  const f16* Bb = WsT + (long long)(j0 + lj) * 512 + quad * 8;
  const long long GS = 512LL * 512;      // gate stride in WsT

  f32x4 g0 = {}, g1 = {}, g2 = {}, g3 = {};

  f16x8 ca = *(const f16x8*)(Ab);
  f16x8 cb0 = *(const f16x8*)(Bb);
  f16x8 cb1 = *(const f16x8*)(Bb + GS);
  f16x8 cb2 = *(const f16x8*)(Bb + 2 * GS);
  f16x8 cb3 = *(const f16x8*)(Bb + 3 * GS);

  #pragma unroll
  for (int kt = 0; kt < 16; kt++) {
    f16x8 na = ca, nb0 = cb0, nb1 = cb1, nb2 = cb2, nb3 = cb3;
    if (kt < 15) {
      const int k = (kt + 1) * 32;
      na  = *(const f16x8*)(Ab + k);
      nb0 = *(const f16x8*)(Bb + k);
      nb1 = *(const f16x8*)(Bb + GS + k);
      nb2 = *(const f16x8*)(Bb + 2 * GS + k);
      nb3 = *(const f16x8*)(Bb + 3 * GS + k);
    }
    g0 = __builtin_amdgcn_mfma_f32_16x16x32_f16(ca, cb0, g0, 0, 0, 0);
    g1 = __builtin_amdgcn_mfma_f32_16x16x32_f16(ca, cb1, g1, 0, 0, 0);
    g2 = __builtin_amdgcn_mfma_f32_16x16x32_f16(ca, cb2, g2, 0, 0, 0);
    g3 = __builtin_amdgcn_mfma_f32_16x16x32_f16(ca, cb3, g3, 0, 0, 0);
    ca = na; cb0 = nb0; cb1 = nb1; cb2 = nb2; cb3 = nb3;
  }

  const float bi = bias[j0 + lj],        bfv = bias[512 + j0 + lj];
  const float bg = bias[1024 + j0 + lj], bo  = bias[1536 + j0 + lj];
  #pragma unroll
  for (int r = 0; r < 4; r++) {
    const int m = m0 + quad * 4 + r;
    const int idx = m * 512 + j0 + lj;
    const float gi = 1.f / (1.f + expf(-(g0[r] + bi)));
    const float gf = 1.f / (1.f + expf(-(g1[r] + bfv)));
    const float gg = fmaxf(g2[r] + bg, 0.f);
    const float go = 1.f / (1.f + expf(-(g3[r] + bo)));
    const float cn = gf * c_prev[idx] + gi * gg;
    const float hn = go * fmaxf(cn, 0.f);
    c_out[idx] = cn;
    h16_out[idx] = (f16)hn;
    if (h32_out) h32_out[idx] = hn;
  }
}

// ---------------------------------------------------------------------------
// L1 gate: reduce nsplit fp16 split-K partials + bias, apply gates.
__global__ __launch_bounds__(256) void gate_kernel(
    const unsigned int* __restrict__ zbase, int nsplit,
    const float* __restrict__ bias,
    const float* __restrict__ c_prev, float* __restrict__ c_out,
    f16* __restrict__ h16_out)
{
  const int idx2 = blockIdx.x * 256 + threadIdx.x;  // 0..65535
  const int b  = idx2 >> 8;
  const int j2 = idx2 & 255;
  const int j  = j2 * 2;
  float z[4][2];
  #pragma unroll
  for (int g = 0; g < 4; g++) { z[g][0] = bias[g * 512 + j]; z[g][1] = bias[g * 512 + j + 1]; }
  for (int s = 0; s < nsplit; s++) {
    const unsigned int* zp = zbase + (long long)s * 262144 + b * 1024;
    #pragma unroll
    for (int g = 0; g < 4; g++) {
      union { unsigned int u; f16 h[2]; } v;
      v.u = zp[g * 256 + j2];
      z[g][0] += (float)v.h[0];
      z[g][1] += (float)v.h[1];
    }
  }
  #pragma unroll
  for (int e = 0; e < 2; e++) {
    const float gi = 1.f / (1.f + expf(-z[0][e]));
    const float gf = 1.f / (1.f + expf(-z[1][e]));
    const float gg = fmaxf(z[2][e], 0.f);
    const float go = 1.f / (1.f + expf(-z[3][e]));
    const int idx = b * 512 + j + e;
    const float cn = gf * c_prev[idx] + gi * gg;
    const float hn = go * fmaxf(cn, 0.f);
    c_out[idx] = cn;
    h16_out[idx] = (f16)hn;
  }
}

// ---------------------------------------------------------------------------
// In-place softmax over V=32000 per row, float4 path. 1024 thr/row.
__global__ __launch_bounds__(1024) void softmax_kernel(
    float* __restrict__ logits, const float* __restrict__ bd)
{
  const int row = blockIdx.x;
  const int t = threadIdx.x;
  float4* rp = (float4*)(logits + (long long)row * 32000);   // 8000 float4
  const float4* bp = (const float4*)bd;
  float4 l[8];
  float m = -1e30f;
  #pragma unroll
  for (int i = 0; i < 8; i++) {
    const int v = t + i * 1024;
    if (v < 8000) {
      float4 x = rp[v]; const float4 bb = bp[v];
      x.x += bb.x; x.y += bb.y; x.z += bb.z; x.w += bb.w;
      l[i] = x;
      m = fmaxf(m, fmaxf(fmaxf(x.x, x.y), fmaxf(x.z, x.w)));
    } else {
      l[i] = make_float4(-1e30f, -1e30f, -1e30f, -1e30f);
    }
  }
  #pragma unroll
  for (int off = 32; off > 0; off >>= 1) m = fmaxf(m, __shfl_xor(m, off, 64));
  __shared__ float redm[16];
  __shared__ float reds[16];
  const int w = t >> 6;
  if ((t & 63) == 0) redm[w] = m;
  __syncthreads();
  float bm = redm[0];
  #pragma unroll
  for (int i = 1; i < 16; i++) bm = fmaxf(bm, redm[i]);
  float s = 0.f;
  #pragma unroll
  for (int i = 0; i < 8; i++) {
    const float ex = expf(l[i].x - bm), ey = expf(l[i].y - bm);
    const float ez = expf(l[i].z - bm), ew = expf(l[i].w - bm);
    l[i] = make_float4(ex, ey, ez, ew);
    s += (ex + ey) + (ez + ew);
  }
  #pragma unroll
  for (int off = 32; off > 0; off >>= 1) s += __shfl_xor(s, off, 64);
  if ((t & 63) == 0) reds[w] = s;
  __syncthreads();
  float ts = 0.f;
  #pragma unroll
  for (int i = 0; i < 16; i++) ts += reds[i];
  const float inv = 1.0f / ts;
  #pragma unroll
  for (int i = 0; i < 8; i++) {
    const int v = t + i * 1024;
    if (v < 8000) {
      float4 x = l[i];
      x.x *= inv; x.y *= inv; x.z *= inv; x.w *= inv;
      rp[v] = x;
    }
  }
}

// ---------------------------------------------------------------------------
extern "C" void kernel_launch(void* const* d_in, const int* in_sizes, int n_in,
                              void* d_out, int out_size, void* d_ws, size_t ws_size,
                              hipStream_t stream) {
  const float* enc     = (const float*)d_in[0];
  const float* word    = (const float*)d_in[1];
  const float* h0      = (const float*)d_in[2];
  const float* c0      = (const float*)d_in[3];
  const int*   speaker = (const int*)d_in[4];
  const float* pers = (const float*)d_in[6];
  const float* W1 = (const float*)d_in[7];
  const float* U1 = (const float*)d_in[8];
  const float* b1 = (const float*)d_in[9];
  const float* W2 = (const float*)d_in[10];
  const float* U2 = (const float*)d_in[11];
  const float* b2 = (const float*)d_in[12];
  const float* W3 = (const float*)d_in[13];
  const float* U3 = (const float*)d_in[14];
  const float* b3 = (const float*)d_in[15];
  const float* W4 = (const float*)d_in[16];
  const float* U4 = (const float*)d_in[17];
  const float* b4 = (const float*)d_in[18];
  const float* Wd = (const float*)d_in[19];
  const float* bd = (const float*)d_in[20];

  float* out = (float*)d_out;
  float* h4_out = out + 8192000;
  float* c4_out = out + 8192000 + 131072;

  // d_ws layout (>= 40 MB used; harness provides ~352 MB):
  f16*   hA   = (f16*)d_ws;                            // 256 KB
  f16*   hB   = (f16*)((char*)d_ws + 262144);          // 256 KB
  f16*   hC   = (f16*)((char*)d_ws + 524288);          // 256 KB
  float* cbuf = (float*)((char*)d_ws + 786432);        // 512 KB
  f16*   WsT  = (f16*)((char*)d_ws + 2097152);         // 6 MB  [2..8 MB)
  f16*   X1h  = (f16*)((char*)d_ws + 8388608);         // 6 MB  [8..14.1 MB)
  f16*   zp16 = (f16*)((char*)d_ws + 16777216);        // 23 MB [16..39 MB)

  const int BIG = 1 << 29;
  const long long LW = 2048LL * 512;

  build_x1_kernel<<<dim3(23, 256), 256, 0, stream>>>(enc, word, pers, speaker, h0, X1h);
  wsum_t_kernel<<<dim3(64, 3), 256, 0, stream>>>(W2, U2, W3, U3, W4, U4, WsT);

  // layer 1: K = 11776 = 23 splits x 512 (16 iters); BM=256 -> B read once
  // per split; grid (16 n-tiles, 23 splits) = 368 blocks
  gemm_pipe2<<<dim3(16, 23), 256, 0, stream>>>(
      X1h, 11776, W1, U1, 11264, 2048, zp16, 2048, 524288LL, 16, 1);
  gate_kernel<<<dim3(256), 256, 0, stream>>>((const unsigned int*)zp16, 23, b1, c0, cbuf, hA);

  // layers 2-4: z = h @ (W+U), K=512, 512 single-wave blocks each
  lstm_small_layer<<<dim3(512), 64, 0, stream>>>(hA, WsT,          b2, cbuf, cbuf, hB, nullptr);
  lstm_small_layer<<<dim3(512), 64, 0, stream>>>(hB, WsT + LW,     b3, cbuf, cbuf, hA, nullptr);
  lstm_small_layer<<<dim3(512), 64, 0, stream>>>(hA, WsT + 2 * LW, b4, cbuf, c4_out, hC, h4_out);

  // decoder: logits = h4 @ Wd fp32; BM=256 -> Wd read exactly once;
  // grid (250 n-tiles, 1) = 250 blocks
  gemm_pipe2<<<dim3(250, 1), 256, 0, stream>>>(
      hC, 512, Wd, Wd, BIG, 32000, out, 32000, 0LL, 16, 0);

  softmax_kernel<<<dim3(256), 1024, 0, stream>>>(out, bd);
}